// Round 13
// baseline (274.963 us; speedup 1.0000x reference)
//
#include <hip/hip_runtime.h>
#include <hip/hip_bf16.h>
#include <cstdint>
#include <cstddef>

#define B_  8
#define N_  1024
#define D_  768
#define H_  12
#define DH_ 64
#define M_  (B_*N_)     // 8192 rows of X
#define D3_ (3*D_)      // 2304

typedef __bf16 bf16;
typedef __bf16 bf16x4 __attribute__((ext_vector_type(4)));
typedef __bf16 bf16x8 __attribute__((ext_vector_type(8)));
typedef float  floatx4 __attribute__((ext_vector_type(4)));
typedef float  floatx16 __attribute__((ext_vector_type(16)));
typedef unsigned int uint32x4 __attribute__((ext_vector_type(4)));

// async global->LDS, 16B/lane; LDS dest = wave-uniform base + lane*16 (m97/m104)
__device__ __forceinline__ void async16(const void* g, void* l) {
  __builtin_amdgcn_global_load_lds(
      (const __attribute__((address_space(1))) unsigned int*)g,
      (__attribute__((address_space(3))) unsigned int*)l, 16, 0, 0);
}

template <int Ncnt> __device__ __forceinline__ void wait_vmcnt() {
  asm volatile("s_waitcnt vmcnt(%0)" :: "n"(Ncnt) : "memory");
}

// ---------- bulk ingest helper (vectorized x4) -------------------------------
__device__ __forceinline__ void ingest_span(const void* src, bf16* dst, int f,
                                            long n4, long i0, long stride) {
  if (f) {
    const ushort2* s = (const ushort2*)src;
    ushort2* d = (ushort2*)dst;
    for (long i = i0; i < n4 * 2; i += stride) d[i] = s[i];
  } else {
    const float4* s = (const float4*)src;
    for (long i = i0; i < n4; i += stride) {
      float4 v = s[i];
      bf16x4 o = { (bf16)v.x, (bf16)v.y, (bf16)v.z, (bf16)v.w };
      *(bf16x4*)(dst + i * 4) = o;
    }
  }
}

// per-block dtype self-detection from x's first 8 KB (L2-hot after block 0).
__device__ __forceinline__ int self_detect(const unsigned int* xraw, int tid,
                                           int* scp) {
  if (tid == 0) *scp = 0;
  __syncthreads();
  int cnt = 0;
#pragma unroll
  for (int j = 0; j < 8; j++) {
    unsigned int w = xraw[tid * 8 + j];
    unsigned int e = (w >> 7) & 0xFF;
    cnt += (e >= 100 && e <= 140) ? 1 : 0;
  }
  atomicAdd(scp, cnt);
  __syncthreads();
  return (*scp > 1024) ? 1 : 0;   // bf16 if low-u16 exponents look normal
}

#define XBLOCKS 1024
#define DBLOCKS 256
#define WTILESA 432            // (D3_/64)*(D_/64)
#define WTILESB 144            // (D_/64)*(D_/64)
#define WTCA    36             // D3_/64

// ---------- merged ingest: x + dist + both weight transposes + small tensors
__global__ __launch_bounds__(256) void ingest_all_k(
    const void* __restrict__ x, bf16* __restrict__ xb,
    const void* __restrict__ dist, bf16* __restrict__ distb,
    const void* __restrict__ WA, bf16* __restrict__ WAT,
    const void* __restrict__ WB, bf16* __restrict__ WBT,
    const void* __restrict__ bq, const void* __restrict__ bp,
    const void* __restrict__ gm,
    int* __restrict__ flag, bf16* __restrict__ bqd, bf16* __restrict__ bpd,
    float* __restrict__ gmd) {
  __shared__ int sc;
  __shared__ bf16 t[64][72];
  int tid = threadIdx.x;
  int f = self_detect((const unsigned int*)x, tid, &sc);
  int bid = blockIdx.x;

  if (bid < XBLOCKS) {
    long i0 = (long)bid * 256 + tid;
    ingest_span(x, xb, f, (long)M_ * D_ / 4, i0, (long)XBLOCKS * 256);
  } else if (bid < XBLOCKS + DBLOCKS) {
    long i0 = (long)(bid - XBLOCKS) * 256 + tid;
    ingest_span(dist, distb, f, (long)N_ * N_ / 4, i0, (long)DBLOCKS * 256);
  } else if (bid < XBLOCKS + DBLOCKS + WTILESA + WTILESB) {
    int wb = bid - (XBLOCKS + DBLOCKS);
    const void* src; bf16* dst; int C; int tc;
    if (wb < WTILESA) { src = WA; dst = WAT; C = D3_; tc = WTCA; }
    else { wb -= WTILESA; src = WB; dst = WBT; C = D_; tc = D_ / 64; }
    int c0 = (wb % tc) * 64, r0 = (wb / tc) * 64;
    int i = tid >> 2, j0 = (tid & 3) * 16;
    if (f) {
      const bf16* s = (const bf16*)src + (size_t)(r0 + i) * C + c0 + j0;
#pragma unroll
      for (int jj = 0; jj < 16; jj += 8)
        *(bf16x8*)&t[i][j0 + jj] = *(const bf16x8*)(s + jj);
    } else {
      const float4* s =
          (const float4*)((const float*)src + (size_t)(r0 + i) * C + c0 + j0);
#pragma unroll
      for (int jj = 0; jj < 4; jj++) {
        float4 v = s[jj];
        bf16x4 o = { (bf16)v.x, (bf16)v.y, (bf16)v.z, (bf16)v.w };
        *(bf16x4*)&t[i][j0 + jj * 4] = o;
      }
    }
    __syncthreads();
    bf16* d = dst + (size_t)(c0 + i) * D_ + r0 + j0;   // R = D_ always
#pragma unroll
    for (int jj = 0; jj < 16; jj++) d[jj] = t[j0 + jj][i];
  } else {
    // small tensors + flag publication
    if (tid == 0) *flag = f;
    for (int i = tid; i < D3_; i += 256)
      bqd[i] = f ? ((const bf16*)bq)[i] : (bf16)((const float*)bq)[i];
    for (int i = tid; i < D_; i += 256)
      bpd[i] = f ? ((const bf16*)bp)[i] : (bf16)((const float*)bp)[i];
    if (tid < B_)
      gmd[tid] = f ? (float)((const bf16*)gm)[tid] : ((const float*)gm)[tid];
  }
}

// ---------------- GEMM: C = A[M][K] * Bt[N][K]^T + bias ----------------------
// R10: 4-buffer depth-3 counted-vmcnt pipeline (T3+T4). One raw s_barrier per
// 32-K step; s_waitcnt vmcnt(2*LPW) keeps 2 K-tiles of global_load_lds in
// flight ACROSS the barrier (never drains to 0 in the main loop; tail
// LPW -> 0). T2: 16B-slot XOR swizzle. T5: setprio around the MFMA cluster.
// R8 epilogue (MODE 0): LDS-staged coalesced stores. R9: Q pre-scaled.
template <int MODE, int TMI, int BYL>
__global__ __launch_bounds__(256) void gemm_bt(const bf16* __restrict__ A,
                                               const bf16* __restrict__ Bt,
                                               const bf16* __restrict__ bias,
                                               bf16* __restrict__ O0,
                                               bf16* __restrict__ O1,
                                               bf16* __restrict__ O2,
                                               float* __restrict__ OF,
                                               const int* __restrict__ flag,
                                               int Kdim) {
  constexpr int TM = TMI * 32;
  constexpr int NBUF = 4;
  constexpr int LPW = TMI / 2 + 2;          // async16 per wave per K-tile
  constexpr int AELEM = NBUF * TM * 32;     // A elems, all buffers
  int id = blockIdx.x;
  int xcd = id & 7;
  int j = id >> 3;
  int bx = j / BYL;                       // n-tile (compile-time divisor)
  int by = xcd * BYL + (j % BYL);         // m-tile: same-XCD blocks share A-slab
  int n0 = bx * 128, m0 = by * TM;
  int tid = threadIdx.x, wave = tid >> 6, lane = tid & 63;
  int wm = (wave >> 1) * (TMI * 16), wn = (wave & 1) * 64;
  int cl = lane & 15, qd = lane >> 4;
  __shared__ __align__(16) bf16 sh[AELEM + NBUF * 128 * 32];
  floatx4 acc[TMI][4] = {};

  int srow = lane >> 2;                           // row within 16-row chunk
  int sko = ((lane & 3) ^ ((srow >> 1) & 3)) * 8; // swizzled 16B slot (T2)

  auto stage = [&](int tk, int buf) {
    int kt = tk * 32;
#pragma unroll
    for (int i = 0; i < TMI / 2; i++) {
      int c = wave * (TMI / 2) + i;
      int row = c * 16 + srow;
      async16(A + (size_t)(m0 + row) * Kdim + kt + sko,
              (char*)sh + buf * (TM * 64) + c * 1024);
    }
#pragma unroll
    for (int i = 0; i < 2; i++) {
      int c = wave * 2 + i;
      int row = c * 16 + srow;
      async16(Bt + (size_t)(n0 + row) * Kdim + kt + sko,
              (char*)sh + (size_t)AELEM * 2 + buf * 8192 + c * 1024);
    }
  };
  auto compute = [&](int buf) {
    const bf16* Ab = sh + buf * (TM * 32);
    const bf16* Bb = sh + AELEM + buf * (128 * 32);
    int ga = (cl >> 1) & 3;                 // read-side swizzle (T2)
    bf16x8 af[TMI], bfv[4];
#pragma unroll
    for (int mi = 0; mi < TMI; mi++)
      af[mi] = *(const bf16x8*)(Ab + (wm + mi * 16 + cl) * 32 + ((qd ^ ga) * 8));
#pragma unroll
    for (int ni = 0; ni < 4; ni++)
      bfv[ni] = *(const bf16x8*)(Bb + (wn + ni * 16 + cl) * 32 + ((qd ^ ga) * 8));
    __builtin_amdgcn_s_setprio(1);
#pragma unroll
    for (int mi = 0; mi < TMI; mi++)
#pragma unroll
      for (int ni = 0; ni < 4; ni++)
        acc[mi][ni] = __builtin_amdgcn_mfma_f32_16x16x32_bf16(af[mi], bfv[ni],
                                                              acc[mi][ni], 0, 0, 0);
    __builtin_amdgcn_s_setprio(0);
  };

  int NT = Kdim >> 5;                       // 32-wide K-tiles (768 -> 24)
  stage(0, 0); stage(1, 1); stage(2, 2);    // depth-3 prologue
  for (int t = 0; t < NT - 3; ++t) {
    wait_vmcnt<2 * LPW>();                  // oldest tile landed (mine)
    __builtin_amdgcn_sched_barrier(0);
    __builtin_amdgcn_s_barrier();           // everyone's share landed
    stage(t + 3, (t + 3) & 3);              // overwrites slot read at t-1
    compute(t & 3);
  }
  wait_vmcnt<2 * LPW>();
  __builtin_amdgcn_sched_barrier(0);
  __builtin_amdgcn_s_barrier();
  compute((NT - 3) & 3);
  wait_vmcnt<LPW>();
  __builtin_amdgcn_sched_barrier(0);
  __builtin_amdgcn_s_barrier();
  compute((NT - 2) & 3);
  wait_vmcnt<0>();
  __builtin_amdgcn_sched_barrier(0);
  __builtin_amdgcn_s_barrier();
  compute((NT - 1) & 3);

  if constexpr (MODE == 0) {
    // -------- coalesced epilogue via LDS transpose (two 64-row halves) -------
    int t = n0 / D_;                   // 0=Q 1=K 2=V (768%128==0 -> uniform)
    int h0 = (n0 % D_) >> 6;           // tile covers heads h0, h0+1
    int b = m0 >> 10;                  // 1024%128==0 -> uniform
    int nbase = m0 & 1023;
    bf16* Ot = (t == 0) ? O0 : O1;
    float qs = (t == 0) ? (0.03608439182435161f * 1.4426950408889634f) : 1.f;
    __syncthreads();                   // all waves done reading As/Bs
#pragma unroll
    for (int hh = 0; hh < 2; hh++) {
      if ((wave >> 1) == hh) {
        // write my 64x64 quadrant, column-major: Ep[col][qpos*4 + r]
#pragma unroll
        for (int ni = 0; ni < 4; ni++) {
          int col = wn + ni * 16 + cl;
          float bv = (float)bias[n0 + col];
          int s = (col >> 3) & 7;
#pragma unroll
          for (int mi = 0; mi < TMI; mi++) {
            int qpos = (mi * 4 + qd) ^ s;
            bf16x4 w = { (bf16)((acc[mi][ni][0] + bv) * qs),
                         (bf16)((acc[mi][ni][1] + bv) * qs),
                         (bf16)((acc[mi][ni][2] + bv) * qs),
                         (bf16)((acc[mi][ni][3] + bv) * qs) };
            *(bf16x4*)((char*)sh + col * 144 + qpos * 8) = w;
          }
        }
      }
      __syncthreads();
      if (t < 2) {
        // rows of [b,h,n,d]: 8-lane groups share (head,row), lane jl -> d=jl*8
#pragma unroll
        for (int it = 0; it < 4; it++) {
          int flat = it * 256 + tid;           // 0..1023
          int rh = flat >> 3, jl = flat & 7;
          int hs = rh >> 6, rl = rh & 63;
          int cb = hs * 64 + jl * 8;
          int s = (cb >> 3) & 7;
          int q = rl >> 2, rr = rl & 3;
          bf16x8 w;
#pragma unroll
          for (int jj = 0; jj < 8; jj++)
            w[jj] = *(const bf16*)((char*)sh + (cb + jj) * 144 + ((q ^ s) * 8) + rr * 2);
          int ng = nbase + hh * 64 + rl;
          *(bf16x8*)(Ot + (((size_t)(b * H_ + h0 + hs) * N_ + ng) * DH_ + jl * 8)) = w;
        }
      } else {
        // rows of V^T [b,h,d,n]: 8-lane groups share col(d), lane jl -> n-chunk
#pragma unroll
        for (int it = 0; it < 4; it++) {
          int flat = it * 256 + tid;           // 0..1023
          int col = flat >> 3, jl = flat & 7;
          int hs = col >> 6, d = col & 63;
          int s = (col >> 3) & 7;
          bf16x4 a0 = *(const bf16x4*)((char*)sh + col * 144 + (((2 * jl) ^ s) * 8));
          bf16x4 a1 = *(const bf16x4*)((char*)sh + col * 144 + (((2 * jl + 1) ^ s) * 8));
          bf16x8 w = { a0[0], a0[1], a0[2], a0[3], a1[0], a1[1], a1[2], a1[3] };
          int ng0 = nbase + hh * 64 + jl * 8;
          *(bf16x8*)(O2 + (((size_t)(b * H_ + h0 + hs) * DH_ + d) * N_ + ng0)) = w;
        }
      }
      __syncthreads();
    }
  } else {
    int fbf16 = *flag;
#pragma unroll
    for (int ni = 0; ni < 4; ni++) {
      int colb = n0 + wn + ni * 16;
      float bv = (float)bias[colb + cl];
#pragma unroll
      for (int mi = 0; mi < TMI; mi++) {
#pragma unroll
        for (int r = 0; r < 4; r++) {
          int row = m0 + wm + mi * 16 + qd * 4 + r;
          float v = acc[mi][ni][r] + bv;
          size_t oi = (size_t)row * D_ + colb + cl;
          if (fbf16) O0[oi] = (bf16)v;
          else       OF[oi] = v;
        }
      }
    }
  }
}

// ---------------- fused flash attention, R19: 64-token tiles, 4 blocks/CU ---
// R12 (dist LDS staging) was the first real attn win (76->70 us); counters
// show VALUBusy 46% at only 2 blocks/CU (66 KB LDS) with a half-idle tail
// round (768 blocks, 3/CU sequential, 2 resident). R19 halves the KV tile to
// 64 tokens: K [64][64]=8KB, V [64][64]=8KB, Ds [128][64]=16KB -> ~33 KB ->
// 4 blocks/CU (16 waves/CU, 2x TLP, no tail). Barrier count doubles - measured
// ~free (R10 null). All swizzles move to 8-slot rows: slot ^ (row&7).
__global__ __launch_bounds__(256, 4) void attn_k(const bf16* __restrict__ Q,
                                                 const bf16* __restrict__ Kp,
                                                 const bf16* __restrict__ Vt,
                                                 const float* __restrict__ gammaf,
                                                 const bf16* __restrict__ dist,
                                                 bf16* __restrict__ O) {
  int bh = blockIdx.x % (B_ * H_);        // idx%8 == bh%8 -> same-bh same XCD
  int q0 = (blockIdx.x / (B_ * H_)) * 128;
  int b = bh / H_, h = bh % H_;
  int tid = threadIdx.x, wave = tid >> 6, lane = tid & 63;
  int l5 = lane & 31, hh = lane >> 5, l7 = lane & 7;
  __shared__ __align__(16) bf16 Ks[64 * 64];    // [token][d], slot ^= row&7
  __shared__ __align__(16) bf16 Vs[64 * 64];    // [d][token], slot ^= row&7
  __shared__ __align__(16) bf16 Ds[128 * 64];   // [q][t],     slot ^= row&7
  __shared__ float Ls[4 * 32];                  // per-wave 1/lsum slab

  // Q B-fragments: row = q (lane&31), k-elems d = st*16 + hh*8 + j
  bf16x8 aq[4];
  {
    const bf16* Qg = Q + ((size_t)bh * N_ + q0 + wave * 32 + l5) * DH_ + hh * 8;
#pragma unroll
    for (int st = 0; st < 4; st++) aq[st] = *(const bf16x8*)(Qg + st * 16);
  }

  floatx16 oacc[2] = {};
  float lsum = 0.f;
  const float LOG2E = 1.4426950408889634f;
  float gl = gammaf[b] * LOG2E;

  const bf16* Kg0 = Kp + (size_t)bh * N_ * DH_;
  const bf16* Vg0 = Vt + (size_t)bh * DH_ * N_;

  // K staging: 512 chunks (row=id>>3 in 0..63, slot=id&7), 2 per thread.
  // V staging: 512 chunks (row=d=id>>3, slot=id&7 -> token slot), 2 per thread.
  int kofs[2], vofs[2];
  const bf16* kg[2]; const bf16* vg[2];
#pragma unroll
  for (int i = 0; i < 2; i++) {
    int id = tid + i * 256;
    int kr = id >> 3, ksl = id & 7;
    kofs[i] = kr * 128 + ((ksl ^ (kr & 7)) * 16);
    kg[i] = Kg0 + (size_t)kr * DH_ + ksl * 8;
    int vr = id >> 3, vsl = id & 7;
    vofs[i] = vr * 128 + ((vsl ^ (vr & 7)) * 16);
    vg[i] = Vg0 + (size_t)vr * N_ + vsl * 8;
  }
  // dist staging: 1024 chunks (row=id>>3 in 0..127, slot=id&7), 4 per thread.
  int dofs[4];
  const bf16* dgp[4];
#pragma unroll
  for (int it = 0; it < 4; it++) {
    int id = tid + it * 256;
    int row = id >> 3, sl = id & 7;
    dofs[it] = row * 128 + ((sl ^ (row & 7)) * 16);
    dgp[it] = dist + (size_t)(q0 + row) * N_ + sl * 8;
  }
  int krd = l5 * 128;     // + sub*4096 + ((st*2+hh)^l7)*16
  int vrd = l5 * 128;     // + t*4096  + ((sub*4+kk*2+hh)^l7)*16
  int dq = wave * 32 + l5;
  int dbase = dq * 128 + hh * 8;   // + ((sub*4+jj)^(dq&7))*16
  int dsw = dq & 7;

  // QK of one sub-tile -> floatx16 (pure MFMA cluster, LDS+reg operands)
#define QKS(SUB, SDST)                                                        \
  do {                                                                        \
    floatx16 s_ = {};                                                         \
    __builtin_amdgcn_s_setprio(1);                                            \
    _Pragma("unroll")                                                         \
    for (int st = 0; st < 4; st++) {                                          \
      bf16x8 ak = *(const bf16x8*)((char*)Ks + (SUB) * 4096 + krd +           \
                                   (((st * 2 + hh) ^ l7) * 16));              \
      s_ = __builtin_amdgcn_mfma_f32_32x32x16_bf16(ak, aq[st], s_, 0, 0, 0);  \
    }                                                                         \
    __builtin_amdgcn_s_setprio(0);                                            \
    SDST = s_;                                                                \
  } while (0)

  // softmax + pack + PV of one sub-tile from SSRC; dist bias from Ds (LDS)
#define SMPV(SUB, SSRC)                                                       \
  do {                                                                        \
    bf16x4 dd[4];                                                             \
    _Pragma("unroll")                                                         \
    for (int jj = 0; jj < 4; jj++)                                            \
      dd[jj] = *(const bf16x4*)((char*)Ds + dbase +                           \
                                ((((SUB) * 4 + jj) ^ dsw) * 16));             \
    float p[16];                                                              \
    _Pragma("unroll")                                                         \
    for (int r = 0; r < 16; r++) {                                            \
      float df = (float)dd[r >> 2][r & 3];                                    \
      p[r] = __builtin_exp2f(__builtin_fmaf(-gl, df, SSRC[r]));               \
      lsum += p[r];                                                           \
    }                                                                         \
    unsigned pw[8];                                                           \
    _Pragma("unroll")                                                         \
    for (int i = 0; i < 8; i++) {                                             \
      unsigned o_;                                                            \
      asm("v_cvt_pk_bf16_f32 %0, %1, %2"                                      \
          : "=v"(o_) : "v"(p[2 * i]), "v"(p[2 * i + 1]));                     \
      pw[i] = o_;                                                             \
    }                                                                         \
    asm("v_permlane32_swap_b32 %0, %1" : "+v"(pw[0]), "+v"(pw[2]));           \
    asm("v_permlane32_swap_b32 %0, %1" : "+v"(pw[1]), "+v"(pw[3]));           \
    asm("v_permlane32_swap_b32 %0, %1" : "+v"(pw[4]), "+v"(pw[6]));           \
    asm("v_permlane32_swap_b32 %0, %1" : "+v"(pw[5]), "+v"(pw[7]));           \
    bf16x8 pa0, pa1;  /* A-frags: A[q=lane&31][k = kk*16 + hh*8 + j] */       \
    { uint32x4 u0 = { pw[0], pw[1], pw[2], pw[3] }; pa0 = *(bf16x8*)&u0; }    \
    { uint32x4 u1 = { pw[4], pw[5], pw[6], pw[7] }; pa1 = *(bf16x8*)&u1; }    \
    __builtin_amdgcn_s_setprio(1);                                            \
    _Pragma("unroll")                                                         \
    for (int t = 0; t < 2; t++) {                                             \
      bf16x8 bv0 = *(const bf16x8*)((char*)Vs + t * 4096 + vrd +              \
                                    ((((SUB) * 4 + hh) ^ l7) * 16));          \
      oacc[t] = __builtin_amdgcn_mfma_f32_32x32x16_bf16(pa0, bv0,             \
                                                        oacc[t], 0, 0, 0);    \
      bf16x8 bv1 = *(const bf16x8*)((char*)Vs + t * 4096 + vrd +              \
                                    ((((SUB) * 4 + 2 + hh) ^ l7) * 16));      \
      oacc[t] = __builtin_amdgcn_mfma_f32_32x32x16_bf16(pa1, bv1,             \
                                                        oacc[t], 0, 0, 0);    \
    }                                                                         \
    __builtin_amdgcn_s_setprio(0);                                            \
  } while (0)

  for (int t0 = 0; t0 < N_; t0 += 64) {
    // issue all global loads for this tile (coalesced; latency overlaps the
    // barrier wait): K 2x16B, V 2x16B, dist 4x16B per thread.
    bf16x8 kv[2], vv[2], dv[4];
#pragma unroll
    for (int i = 0; i < 2; i++) kv[i] = *(const bf16x8*)(kg[i] + (size_t)t0 * DH_);
#pragma unroll
    for (int i = 0; i < 2; i++) vv[i] = *(const bf16x8*)(vg[i] + t0);
#pragma unroll
    for (int it = 0; it < 4; it++) dv[it] = *(const bf16x8*)(dgp[it] + t0);

    __syncthreads();      // all waves done reading Ks/Vs/Ds of previous tile
#pragma unroll
    for (int i = 0; i < 2; i++) *(bf16x8*)((char*)Ks + kofs[i]) = kv[i];
#pragma unroll
    for (int i = 0; i < 2; i++) *(bf16x8*)((char*)Vs + vofs[i]) = vv[i];
#pragma unroll
    for (int it = 0; it < 4; it++) *(bf16x8*)((char*)Ds + dofs[it]) = dv[it];
    __syncthreads();      // tile visible

    // 2-deep pipeline across the 2 sub-tiles
    floatx16 sA, sB;
    QKS(0, sA);
    QKS(1, sB);
    SMPV(0, sA);
    SMPV(1, sB);
  }
#undef QKS
#undef SMPV

  // lsum(q) = lo-half + hi-half partial sums; broadcast 1/lsum via LDS slab
  lsum += __shfl_xor(lsum, 32, 64);
  float inv = 1.f / lsum;
  Ls[wave * 32 + l5] = inv;         // lanes l, l+32 write same value: benign
  __syncthreads();
  size_t obase = ((size_t)b * N_ + q0 + wave * 32) * D_ + h * DH_;
#pragma unroll
  for (int r = 0; r < 16; r++) {
    int qrow = (r & 3) + 8 * (r >> 2) + 4 * hh;
    float iv = Ls[wave * 32 + qrow];
#pragma unroll
    for (int t = 0; t < 2; t++)
      O[obase + (size_t)qrow * D_ + t * 32 + l5] = (bf16)(oacc[t][r] * iv);
  }
}

extern "C" void kernel_launch(void* const* d_in, const int* in_sizes, int n_in,
                              void* d_out, int out_size, void* d_ws, size_t ws_size,
                              hipStream_t stream) {
  const void* x     = d_in[0];
  const void* gamma = d_in[1];
  const void* dist  = d_in[2];
  const void* Wqkv  = d_in[3];
  const void* bqkv  = d_in[4];
  const void* Wproj = d_in[5];
  const void* bproj = d_in[6];

  char* ws = (char*)d_ws;
  size_t o = 0;
  int*   flag   = (int*)(ws + o);   o += 16;
  float* gammaf = (float*)(ws + o); o += 32;
  bf16*  xb     = (bf16*)(ws + o);  o += (size_t)M_ * D_ * 2;
  bf16*  distb  = (bf16*)(ws + o);  o += (size_t)N_ * N_ * 2;
  bf16*  bqkvb  = (bf16*)(ws + o);  o += (size_t)D3_ * 2;
  bf16*  bprojb = (bf16*)(ws + o);  o += (size_t)D_ * 2 + 8;
  bf16*  WqkvT  = (bf16*)(ws + o);  o += (size_t)D3_ * D_ * 2;
  bf16*  WprojT = (bf16*)(ws + o);  o += (size_t)D_ * D_ * 2;
  bf16*  Qp     = (bf16*)(ws + o);  o += (size_t)M_ * D_ * 2;
  bf16*  Kp     = (bf16*)(ws + o);  o += (size_t)M_ * D_ * 2;
  bf16*  Vtp    = (bf16*)(ws + o);  o += (size_t)M_ * D_ * 2;
  bf16*  Op     = (bf16*)(ws + o);  o += (size_t)M_ * D_ * 2;
  if (ws_size < o) return;

  // one merged ingest launch: x + dist + both weight transposes + small tensors
  ingest_all_k<<<XBLOCKS + DBLOCKS + WTILESA + WTILESB + 1, 256, 0, stream>>>(
      x, xb, dist, distb, Wqkv, WqkvT, Wproj, WprojT, bqkv, bproj, gamma,
      flag, bqkvb, bprojb, gammaf);

  // QKV: grid 18 x 64 -> 1D 1152, BYL = 64/8 = 8
  gemm_bt<0, 4, 8><<<18 * 64, 256, 0, stream>>>(
      xb, WqkvT, bqkvb, Qp, Kp, Vtp, nullptr, flag, D_);
  attn_k<<<dim3(B_ * H_ * (N_ / 128)), 256, 0, stream>>>(
      Qp, Kp, Vtp, gammaf, distb, Op);
  // proj: grid 6 x 128 -> 1D 768, BYL = 128/8 = 16
  gemm_bt<1, 2, 16><<<6 * 128, 256, 0, stream>>>(
      Op, WprojT, bprojb, (bf16*)d_out, nullptr, nullptr, (float*)d_out, flag, D_);
}

// Round 14
// 237.305 us; speedup vs baseline: 1.1587x; 1.1587x over previous
//
#include <hip/hip_runtime.h>
#include <hip/hip_bf16.h>
#include <cstdint>
#include <cstddef>

#define B_  8
#define N_  1024
#define D_  768
#define H_  12
#define DH_ 64
#define M_  (B_*N_)     // 8192 rows of X
#define D3_ (3*D_)      // 2304

typedef __bf16 bf16;
typedef __bf16 bf16x4 __attribute__((ext_vector_type(4)));
typedef __bf16 bf16x8 __attribute__((ext_vector_type(8)));
typedef float  floatx4 __attribute__((ext_vector_type(4)));
typedef float  floatx16 __attribute__((ext_vector_type(16)));
typedef unsigned int uint32x4 __attribute__((ext_vector_type(4)));

// async global->LDS, 16B/lane; LDS dest = wave-uniform base + lane*16 (m97/m104)
__device__ __forceinline__ void async16(const void* g, void* l) {
  __builtin_amdgcn_global_load_lds(
      (const __attribute__((address_space(1))) unsigned int*)g,
      (__attribute__((address_space(3))) unsigned int*)l, 16, 0, 0);
}

template <int Ncnt> __device__ __forceinline__ void wait_vmcnt() {
  asm volatile("s_waitcnt vmcnt(%0)" :: "n"(Ncnt) : "memory");
}

// ---------- bulk ingest helper (vectorized x4) -------------------------------
__device__ __forceinline__ void ingest_span(const void* src, bf16* dst, int f,
                                            long n4, long i0, long stride) {
  if (f) {
    const ushort2* s = (const ushort2*)src;
    ushort2* d = (ushort2*)dst;
    for (long i = i0; i < n4 * 2; i += stride) d[i] = s[i];
  } else {
    const float4* s = (const float4*)src;
    for (long i = i0; i < n4; i += stride) {
      float4 v = s[i];
      bf16x4 o = { (bf16)v.x, (bf16)v.y, (bf16)v.z, (bf16)v.w };
      *(bf16x4*)(dst + i * 4) = o;
    }
  }
}

// per-block dtype self-detection from x's first 8 KB (L2-hot after block 0).
__device__ __forceinline__ int self_detect(const unsigned int* xraw, int tid,
                                           int* scp) {
  if (tid == 0) *scp = 0;
  __syncthreads();
  int cnt = 0;
#pragma unroll
  for (int j = 0; j < 8; j++) {
    unsigned int w = xraw[tid * 8 + j];
    unsigned int e = (w >> 7) & 0xFF;
    cnt += (e >= 100 && e <= 140) ? 1 : 0;
  }
  atomicAdd(scp, cnt);
  __syncthreads();
  return (*scp > 1024) ? 1 : 0;   // bf16 if low-u16 exponents look normal
}

#define XBLOCKS 1024
#define DBLOCKS 256
#define WTILESA 432            // (D3_/64)*(D_/64)
#define WTILESB 144            // (D_/64)*(D_/64)
#define WTCA    36             // D3_/64

// ---------- merged ingest: x + dist + both weight transposes + small tensors
__global__ __launch_bounds__(256) void ingest_all_k(
    const void* __restrict__ x, bf16* __restrict__ xb,
    const void* __restrict__ dist, bf16* __restrict__ distb,
    const void* __restrict__ WA, bf16* __restrict__ WAT,
    const void* __restrict__ WB, bf16* __restrict__ WBT,
    const void* __restrict__ bq, const void* __restrict__ bp,
    const void* __restrict__ gm,
    int* __restrict__ flag, bf16* __restrict__ bqd, bf16* __restrict__ bpd,
    float* __restrict__ gmd) {
  __shared__ int sc;
  __shared__ bf16 t[64][72];
  int tid = threadIdx.x;
  int f = self_detect((const unsigned int*)x, tid, &sc);
  int bid = blockIdx.x;

  if (bid < XBLOCKS) {
    long i0 = (long)bid * 256 + tid;
    ingest_span(x, xb, f, (long)M_ * D_ / 4, i0, (long)XBLOCKS * 256);
  } else if (bid < XBLOCKS + DBLOCKS) {
    long i0 = (long)(bid - XBLOCKS) * 256 + tid;
    ingest_span(dist, distb, f, (long)N_ * N_ / 4, i0, (long)DBLOCKS * 256);
  } else if (bid < XBLOCKS + DBLOCKS + WTILESA + WTILESB) {
    int wb = bid - (XBLOCKS + DBLOCKS);
    const void* src; bf16* dst; int C; int tc;
    if (wb < WTILESA) { src = WA; dst = WAT; C = D3_; tc = WTCA; }
    else { wb -= WTILESA; src = WB; dst = WBT; C = D_; tc = D_ / 64; }
    int c0 = (wb % tc) * 64, r0 = (wb / tc) * 64;
    int i = tid >> 2, j0 = (tid & 3) * 16;
    if (f) {
      const bf16* s = (const bf16*)src + (size_t)(r0 + i) * C + c0 + j0;
#pragma unroll
      for (int jj = 0; jj < 16; jj += 8)
        *(bf16x8*)&t[i][j0 + jj] = *(const bf16x8*)(s + jj);
    } else {
      const float4* s =
          (const float4*)((const float*)src + (size_t)(r0 + i) * C + c0 + j0);
#pragma unroll
      for (int jj = 0; jj < 4; jj++) {
        float4 v = s[jj];
        bf16x4 o = { (bf16)v.x, (bf16)v.y, (bf16)v.z, (bf16)v.w };
        *(bf16x4*)&t[i][j0 + jj * 4] = o;
      }
    }
    __syncthreads();
    bf16* d = dst + (size_t)(c0 + i) * D_ + r0 + j0;   // R = D_ always
#pragma unroll
    for (int jj = 0; jj < 16; jj++) d[jj] = t[j0 + jj][i];
  } else {
    // small tensors + flag publication
    if (tid == 0) *flag = f;
    for (int i = tid; i < D3_; i += 256)
      bqd[i] = f ? ((const bf16*)bq)[i] : (bf16)((const float*)bq)[i];
    for (int i = tid; i < D_; i += 256)
      bpd[i] = f ? ((const bf16*)bp)[i] : (bf16)((const float*)bp)[i];
    if (tid < B_)
      gmd[tid] = f ? (float)((const bf16*)gm)[tid] : ((const float*)gm)[tid];
  }
}

// ---------------- GEMM: C = A[M][K] * Bt[N][K]^T + bias ----------------------
// R10: 4-buffer depth-3 counted-vmcnt pipeline (T3+T4). One raw s_barrier per
// 32-K step; s_waitcnt vmcnt(2*LPW) keeps 2 K-tiles of global_load_lds in
// flight ACROSS the barrier (never drains to 0 in the main loop; tail
// LPW -> 0). T2: 16B-slot XOR swizzle. T5: setprio around the MFMA cluster.
// R8 epilogue (MODE 0): LDS-staged coalesced stores. R9: Q pre-scaled.
template <int MODE, int TMI, int BYL>
__global__ __launch_bounds__(256) void gemm_bt(const bf16* __restrict__ A,
                                               const bf16* __restrict__ Bt,
                                               const bf16* __restrict__ bias,
                                               bf16* __restrict__ O0,
                                               bf16* __restrict__ O1,
                                               bf16* __restrict__ O2,
                                               float* __restrict__ OF,
                                               const int* __restrict__ flag,
                                               int Kdim) {
  constexpr int TM = TMI * 32;
  constexpr int NBUF = 4;
  constexpr int LPW = TMI / 2 + 2;          // async16 per wave per K-tile
  constexpr int AELEM = NBUF * TM * 32;     // A elems, all buffers
  int id = blockIdx.x;
  int xcd = id & 7;
  int j = id >> 3;
  int bx = j / BYL;                       // n-tile (compile-time divisor)
  int by = xcd * BYL + (j % BYL);         // m-tile: same-XCD blocks share A-slab
  int n0 = bx * 128, m0 = by * TM;
  int tid = threadIdx.x, wave = tid >> 6, lane = tid & 63;
  int wm = (wave >> 1) * (TMI * 16), wn = (wave & 1) * 64;
  int cl = lane & 15, qd = lane >> 4;
  __shared__ __align__(16) bf16 sh[AELEM + NBUF * 128 * 32];
  floatx4 acc[TMI][4] = {};

  int srow = lane >> 2;                           // row within 16-row chunk
  int sko = ((lane & 3) ^ ((srow >> 1) & 3)) * 8; // swizzled 16B slot (T2)

  auto stage = [&](int tk, int buf) {
    int kt = tk * 32;
#pragma unroll
    for (int i = 0; i < TMI / 2; i++) {
      int c = wave * (TMI / 2) + i;
      int row = c * 16 + srow;
      async16(A + (size_t)(m0 + row) * Kdim + kt + sko,
              (char*)sh + buf * (TM * 64) + c * 1024);
    }
#pragma unroll
    for (int i = 0; i < 2; i++) {
      int c = wave * 2 + i;
      int row = c * 16 + srow;
      async16(Bt + (size_t)(n0 + row) * Kdim + kt + sko,
              (char*)sh + (size_t)AELEM * 2 + buf * 8192 + c * 1024);
    }
  };
  auto compute = [&](int buf) {
    const bf16* Ab = sh + buf * (TM * 32);
    const bf16* Bb = sh + AELEM + buf * (128 * 32);
    int ga = (cl >> 1) & 3;                 // read-side swizzle (T2)
    bf16x8 af[TMI], bfv[4];
#pragma unroll
    for (int mi = 0; mi < TMI; mi++)
      af[mi] = *(const bf16x8*)(Ab + (wm + mi * 16 + cl) * 32 + ((qd ^ ga) * 8));
#pragma unroll
    for (int ni = 0; ni < 4; ni++)
      bfv[ni] = *(const bf16x8*)(Bb + (wn + ni * 16 + cl) * 32 + ((qd ^ ga) * 8));
    __builtin_amdgcn_s_setprio(1);
#pragma unroll
    for (int mi = 0; mi < TMI; mi++)
#pragma unroll
      for (int ni = 0; ni < 4; ni++)
        acc[mi][ni] = __builtin_amdgcn_mfma_f32_16x16x32_bf16(af[mi], bfv[ni],
                                                              acc[mi][ni], 0, 0, 0);
    __builtin_amdgcn_s_setprio(0);
  };

  int NT = Kdim >> 5;                       // 32-wide K-tiles (768 -> 24)
  stage(0, 0); stage(1, 1); stage(2, 2);    // depth-3 prologue
  for (int t = 0; t < NT - 3; ++t) {
    wait_vmcnt<2 * LPW>();                  // oldest tile landed (mine)
    __builtin_amdgcn_sched_barrier(0);
    __builtin_amdgcn_s_barrier();           // everyone's share landed
    stage(t + 3, (t + 3) & 3);              // overwrites slot read at t-1
    compute(t & 3);
  }
  wait_vmcnt<2 * LPW>();
  __builtin_amdgcn_sched_barrier(0);
  __builtin_amdgcn_s_barrier();
  compute((NT - 3) & 3);
  wait_vmcnt<LPW>();
  __builtin_amdgcn_sched_barrier(0);
  __builtin_amdgcn_s_barrier();
  compute((NT - 2) & 3);
  wait_vmcnt<0>();
  __builtin_amdgcn_sched_barrier(0);
  __builtin_amdgcn_s_barrier();
  compute((NT - 1) & 3);

  if constexpr (MODE == 0) {
    // -------- coalesced epilogue via LDS transpose (two 64-row halves) -------
    int t = n0 / D_;                   // 0=Q 1=K 2=V (768%128==0 -> uniform)
    int h0 = (n0 % D_) >> 6;           // tile covers heads h0, h0+1
    int b = m0 >> 10;                  // 1024%128==0 -> uniform
    int nbase = m0 & 1023;
    bf16* Ot = (t == 0) ? O0 : O1;
    float qs = (t == 0) ? (0.03608439182435161f * 1.4426950408889634f) : 1.f;
    __syncthreads();                   // all waves done reading As/Bs
#pragma unroll
    for (int hh = 0; hh < 2; hh++) {
      if ((wave >> 1) == hh) {
        // write my 64x64 quadrant, column-major: Ep[col][qpos*4 + r]
#pragma unroll
        for (int ni = 0; ni < 4; ni++) {
          int col = wn + ni * 16 + cl;
          float bv = (float)bias[n0 + col];
          int s = (col >> 3) & 7;
#pragma unroll
          for (int mi = 0; mi < TMI; mi++) {
            int qpos = (mi * 4 + qd) ^ s;
            bf16x4 w = { (bf16)((acc[mi][ni][0] + bv) * qs),
                         (bf16)((acc[mi][ni][1] + bv) * qs),
                         (bf16)((acc[mi][ni][2] + bv) * qs),
                         (bf16)((acc[mi][ni][3] + bv) * qs) };
            *(bf16x4*)((char*)sh + col * 144 + qpos * 8) = w;
          }
        }
      }
      __syncthreads();
      if (t < 2) {
        // rows of [b,h,n,d]: 8-lane groups share (head,row), lane jl -> d=jl*8
#pragma unroll
        for (int it = 0; it < 4; it++) {
          int flat = it * 256 + tid;           // 0..1023
          int rh = flat >> 3, jl = flat & 7;
          int hs = rh >> 6, rl = rh & 63;
          int cb = hs * 64 + jl * 8;
          int s = (cb >> 3) & 7;
          int q = rl >> 2, rr = rl & 3;
          bf16x8 w;
#pragma unroll
          for (int jj = 0; jj < 8; jj++)
            w[jj] = *(const bf16*)((char*)sh + (cb + jj) * 144 + ((q ^ s) * 8) + rr * 2);
          int ng = nbase + hh * 64 + rl;
          *(bf16x8*)(Ot + (((size_t)(b * H_ + h0 + hs) * N_ + ng) * DH_ + jl * 8)) = w;
        }
      } else {
        // rows of V^T [b,h,d,n]: 8-lane groups share col(d), lane jl -> n-chunk
#pragma unroll
        for (int it = 0; it < 4; it++) {
          int flat = it * 256 + tid;           // 0..1023
          int col = flat >> 3, jl = flat & 7;
          int hs = col >> 6, d = col & 63;
          int s = (col >> 3) & 7;
          bf16x4 a0 = *(const bf16x4*)((char*)sh + col * 144 + (((2 * jl) ^ s) * 8));
          bf16x4 a1 = *(const bf16x4*)((char*)sh + col * 144 + (((2 * jl + 1) ^ s) * 8));
          bf16x8 w = { a0[0], a0[1], a0[2], a0[3], a1[0], a1[1], a1[2], a1[3] };
          int ng0 = nbase + hh * 64 + jl * 8;
          *(bf16x8*)(O2 + (((size_t)(b * H_ + h0 + hs) * DH_ + d) * N_ + ng0)) = w;
        }
      }
      __syncthreads();
    }
  } else {
    int fbf16 = *flag;
#pragma unroll
    for (int ni = 0; ni < 4; ni++) {
      int colb = n0 + wn + ni * 16;
      float bv = (float)bias[colb + cl];
#pragma unroll
      for (int mi = 0; mi < TMI; mi++) {
#pragma unroll
        for (int r = 0; r < 4; r++) {
          int row = m0 + wm + mi * 16 + qd * 4 + r;
          float v = acc[mi][ni][r] + bv;
          size_t oi = (size_t)row * D_ + colb + cl;
          if (fbf16) O0[oi] = (bf16)v;
          else       OF[oi] = v;
        }
      }
    }
  }
}

// ---------------- fused flash attention, R20 = R12 (session best, 70 us) ----
// R12: dist LDS staging fixed the scattered 2KB-stride gather (16x cache-line
// amplification, ~0.8 GB L2 traffic) -> 76->70 us, the one real attn win.
// R13's 64-token tile at (256,4) spilled (VGPR clamped to 64, WRITE 74 MB).
// Restored verbatim: 128-token tiles, Ks/Vs/Ds LDS (66 KB, 2 blocks/CU),
// 2-deep QK/SMPV pipeline, (256,2).
__global__ __launch_bounds__(256, 2) void attn_k(const bf16* __restrict__ Q,
                                                 const bf16* __restrict__ Kp,
                                                 const bf16* __restrict__ Vt,
                                                 const float* __restrict__ gammaf,
                                                 const bf16* __restrict__ dist,
                                                 bf16* __restrict__ O) {
  int bh = blockIdx.x % (B_ * H_);        // idx%8 == bh%8 -> same-bh same XCD
  int q0 = (blockIdx.x / (B_ * H_)) * 128;
  int b = bh / H_, h = bh % H_;
  int tid = threadIdx.x, wave = tid >> 6, lane = tid & 63;
  int l5 = lane & 31, hh = lane >> 5, l7 = lane & 7;
  __shared__ __align__(16) bf16 Ks[128 * 64];   // [token][d], 16B slots XOR row&7
  __shared__ __align__(16) bf16 Vs[64 * 128];   // [d][token], 16B slots XOR row&7
  __shared__ __align__(16) bf16 Ds[128 * 128];  // [q][t], 16B slot ^ ((q>>1)&15)
  __shared__ float Ls[4 * 32];                  // per-wave 1/lsum slab

  // Q B-fragments: row = q (lane&31), k-elems d = st*16 + hh*8 + j
  bf16x8 aq[4];
  {
    const bf16* Qg = Q + ((size_t)bh * N_ + q0 + wave * 32 + l5) * DH_ + hh * 8;
#pragma unroll
    for (int st = 0; st < 4; st++) aq[st] = *(const bf16x8*)(Qg + st * 16);
  }

  floatx16 oacc[2] = {};
  float lsum = 0.f;
  const float LOG2E = 1.4426950408889634f;
  float gl = gammaf[b] * LOG2E;

  const bf16* Kg0 = Kp + (size_t)bh * N_ * DH_;
  const bf16* Vg0 = Vt + (size_t)bh * DH_ * N_;

  // K/V staging: thread t owns 4 K-slots (id>>3 = row, id&7 = slot) and 4
  // V-slots (id>>4 = row, id&15 = slot); LDS position swizzled, global linear.
  int kofs[4], vofs[4];
  const bf16* kg[4]; const bf16* vg[4];
#pragma unroll
  for (int i = 0; i < 4; i++) {
    int id = tid + i * 256;
    int kr = id >> 3, ksl = id & 7;
    kofs[i] = kr * 128 + ((ksl ^ (kr & 7)) * 16);
    kg[i] = Kg0 + (size_t)kr * DH_ + ksl * 8;
    int vr = id >> 4, vsl = id & 15;
    vofs[i] = vr * 256 + ((vsl ^ (vr & 7)) * 16);
    vg[i] = Vg0 + (size_t)vr * N_ + vsl * 8;
  }
  int krd = l5 * 128;     // + sub*4096 + ((st*2+hh)^l7)*16
  int vrd = l5 * 256;     // + t*8192  + ((sub*4+kk*2+hh)^l7)*16

  // dist staging: thread owns 8 x 16B chunks; row = (tid>>4)+it*16, sl = tid&15
  // src rows contiguous (coalesced); LDS slot16 XOR-swizzled by (row>>1)&15.
  int drow = tid >> 4, dsl = tid & 15;
  const bf16* dg0 = dist + (size_t)(q0 + drow) * N_ + dsl * 8;
  int dofs[8];
#pragma unroll
  for (int it = 0; it < 8; it++) {
    int row = drow + it * 16;
    dofs[it] = row * 256 + ((dsl ^ ((row >> 1) & 15)) * 16);
  }
  // read-side: lane's q and swizzle base
  int dq = wave * 32 + l5;
  int dbase = dq * 256 + hh * 8;
  int dsw = (dq >> 1) & 15;

  // QK of one sub-tile -> floatx16 (pure MFMA cluster, LDS+reg operands)
#define QKS(SUB, SDST)                                                        \
  do {                                                                        \
    floatx16 s_ = {};                                                         \
    __builtin_amdgcn_s_setprio(1);                                            \
    _Pragma("unroll")                                                         \
    for (int st = 0; st < 4; st++) {                                          \
      bf16x8 ak = *(const bf16x8*)((char*)Ks + (SUB) * 4096 + krd +           \
                                   (((st * 2 + hh) ^ l7) * 16));              \
      s_ = __builtin_amdgcn_mfma_f32_32x32x16_bf16(ak, aq[st], s_, 0, 0, 0);  \
    }                                                                         \
    __builtin_amdgcn_s_setprio(0);                                            \
    SDST = s_;                                                                \
  } while (0)

  // softmax + pack + PV of one sub-tile from SSRC; dist bias from Ds (LDS)
#define SMPV(SUB, SSRC)                                                       \
  do {                                                                        \
    bf16x4 dd[4];                                                             \
    _Pragma("unroll")                                                         \
    for (int jj = 0; jj < 4; jj++)                                            \
      dd[jj] = *(const bf16x4*)((char*)Ds + dbase +                           \
                                ((((SUB) * 4 + jj) ^ dsw) * 16));             \
    float p[16];                                                              \
    _Pragma("unroll")                                                         \
    for (int r = 0; r < 16; r++) {                                            \
      float df = (float)dd[r >> 2][r & 3];                                    \
      p[r] = __builtin_exp2f(__builtin_fmaf(-gl, df, SSRC[r]));               \
      lsum += p[r];                                                           \
    }                                                                         \
    unsigned pw[8];                                                           \
    _Pragma("unroll")                                                         \
    for (int i = 0; i < 8; i++) {                                             \
      unsigned o_;                                                            \
      asm("v_cvt_pk_bf16_f32 %0, %1, %2"                                      \
          : "=v"(o_) : "v"(p[2 * i]), "v"(p[2 * i + 1]));                     \
      pw[i] = o_;                                                             \
    }                                                                         \
    asm("v_permlane32_swap_b32 %0, %1" : "+v"(pw[0]), "+v"(pw[2]));           \
    asm("v_permlane32_swap_b32 %0, %1" : "+v"(pw[1]), "+v"(pw[3]));           \
    asm("v_permlane32_swap_b32 %0, %1" : "+v"(pw[4]), "+v"(pw[6]));           \
    asm("v_permlane32_swap_b32 %0, %1" : "+v"(pw[5]), "+v"(pw[7]));           \
    bf16x8 pa0, pa1;  /* A-frags: A[q=lane&31][k = kk*16 + hh*8 + j] */       \
    { uint32x4 u0 = { pw[0], pw[1], pw[2], pw[3] }; pa0 = *(bf16x8*)&u0; }    \
    { uint32x4 u1 = { pw[4], pw[5], pw[6], pw[7] }; pa1 = *(bf16x8*)&u1; }    \
    __builtin_amdgcn_s_setprio(1);                                            \
    _Pragma("unroll")                                                         \
    for (int t = 0; t < 2; t++) {                                             \
      bf16x8 bv0 = *(const bf16x8*)((char*)Vs + t * 8192 + vrd +              \
                                    ((((SUB) * 4 + hh) ^ l7) * 16));          \
      oacc[t] = __builtin_amdgcn_mfma_f32_32x32x16_bf16(pa0, bv0,             \
                                                        oacc[t], 0, 0, 0);    \
      bf16x8 bv1 = *(const bf16x8*)((char*)Vs + t * 8192 + vrd +              \
                                    ((((SUB) * 4 + 2 + hh) ^ l7) * 16));      \
      oacc[t] = __builtin_amdgcn_mfma_f32_32x32x16_bf16(pa1, bv1,             \
                                                        oacc[t], 0, 0, 0);    \
    }                                                                         \
    __builtin_amdgcn_s_setprio(0);                                            \
  } while (0)

  for (int t0 = 0; t0 < N_; t0 += 128) {
    // issue all global loads for this tile (coalesced; latency overlaps
    // the barrier wait). dist rows are contiguous 16B chunks now.
    bf16x8 kv[4], vv[4], dv[8];
#pragma unroll
    for (int i = 0; i < 4; i++) kv[i] = *(const bf16x8*)(kg[i] + (size_t)t0 * DH_);
#pragma unroll
    for (int i = 0; i < 4; i++) vv[i] = *(const bf16x8*)(vg[i] + t0);
#pragma unroll
    for (int it = 0; it < 8; it++)
      dv[it] = *(const bf16x8*)(dg0 + (size_t)(it * 16) * N_ + t0);

    __syncthreads();      // all waves done reading Ks/Vs/Ds of previous tile
#pragma unroll
    for (int i = 0; i < 4; i++) *(bf16x8*)((char*)Ks + kofs[i]) = kv[i];
#pragma unroll
    for (int i = 0; i < 4; i++) *(bf16x8*)((char*)Vs + vofs[i]) = vv[i];
#pragma unroll
    for (int it = 0; it < 8; it++) *(bf16x8*)((char*)Ds + dofs[it]) = dv[it];
    __syncthreads();      // tile visible

    // 2-deep software pipeline across the 4 sub-tiles: QK of sub s+1 is
    // issued before softmax/PV of sub s (matrix pipe fills while VALU works).
    floatx16 sA, sB;
    QKS(0, sA);
    QKS(1, sB);
    SMPV(0, sA);
    QKS(2, sA);
    SMPV(1, sB);
    QKS(3, sB);
    SMPV(2, sA);
    SMPV(3, sB);
  }
#undef QKS
#undef SMPV

  // lsum(q) = lo-half + hi-half partial sums; broadcast 1/lsum via LDS slab
  lsum += __shfl_xor(lsum, 32, 64);
  float inv = 1.f / lsum;
  Ls[wave * 32 + l5] = inv;         // lanes l, l+32 write same value: benign
  __syncthreads();
  size_t obase = ((size_t)b * N_ + q0 + wave * 32) * D_ + h * DH_;
#pragma unroll
  for (int r = 0; r < 16; r++) {
    int qrow = (r & 3) + 8 * (r >> 2) + 4 * hh;
    float iv = Ls[wave * 32 + qrow];
#pragma unroll
    for (int t = 0; t < 2; t++)
      O[obase + (size_t)qrow * D_ + t * 32 + l5] = (bf16)(oacc[t][r] * iv);
  }
}

extern "C" void kernel_launch(void* const* d_in, const int* in_sizes, int n_in,
                              void* d_out, int out_size, void* d_ws, size_t ws_size,
                              hipStream_t stream) {
  const void* x     = d_in[0];
  const void* gamma = d_in[1];
  const void* dist  = d_in[2];
  const void* Wqkv  = d_in[3];
  const void* bqkv  = d_in[4];
  const void* Wproj = d_in[5];
  const void* bproj = d_in[6];

  char* ws = (char*)d_ws;
  size_t o = 0;
  int*   flag   = (int*)(ws + o);   o += 16;
  float* gammaf = (float*)(ws + o); o += 32;
  bf16*  xb     = (bf16*)(ws + o);  o += (size_t)M_ * D_ * 2;
  bf16*  distb  = (bf16*)(ws + o);  o += (size_t)N_ * N_ * 2;
  bf16*  bqkvb  = (bf16*)(ws + o);  o += (size_t)D3_ * 2;
  bf16*  bprojb = (bf16*)(ws + o);  o += (size_t)D_ * 2 + 8;
  bf16*  WqkvT  = (bf16*)(ws + o);  o += (size_t)D3_ * D_ * 2;
  bf16*  WprojT = (bf16*)(ws + o);  o += (size_t)D_ * D_ * 2;
  bf16*  Qp     = (bf16*)(ws + o);  o += (size_t)M_ * D_ * 2;
  bf16*  Kp     = (bf16*)(ws + o);  o += (size_t)M_ * D_ * 2;
  bf16*  Vtp    = (bf16*)(ws + o);  o += (size_t)M_ * D_ * 2;
  bf16*  Op     = (bf16*)(ws + o);  o += (size_t)M_ * D_ * 2;
  if (ws_size < o) return;

  // one merged ingest launch: x + dist + both weight transposes + small tensors
  ingest_all_k<<<XBLOCKS + DBLOCKS + WTILESA + WTILESB + 1, 256, 0, stream>>>(
      x, xb, dist, distb, Wqkv, WqkvT, Wproj, WprojT, bqkv, bproj, gamma,
      flag, bqkvb, bprojb, gammaf);

  // QKV: grid 18 x 64 -> 1D 1152, BYL = 64/8 = 8
  gemm_bt<0, 4, 8><<<18 * 64, 256, 0, stream>>>(
      xb, WqkvT, bqkvb, Qp, Kp, Vtp, nullptr, flag, D_);
  attn_k<<<dim3(B_ * H_ * (N_ / 128)), 256, 0, stream>>>(
      Qp, Kp, Vtp, gammaf, distb, Op);
  // proj: grid 6 x 128 -> 1D 768, BYL = 128/8 = 16
  gemm_bt<1, 2, 16><<<6 * 128, 256, 0, stream>>>(
      Op, WprojT, bprojb, (bf16*)d_out, nullptr, nullptr, (float*)d_out, flag, D_);
}